// Round 13
// baseline (283.654 us; speedup 1.0000x reference)
//
#include <hip/hip_runtime.h>
#include <float.h>
#include <limits.h>

#define N_Q 8192
#define M_PTS 50000
#define DIM 128
#define KNN 10
#define NCLS 10
#define NCHUNK 16          // 16 chunks x 196 tiles (3136 tiles, 11 padded)
#define TPC 196            // tiles per chunk (uniform, compile-time)
#define CPC 8              // candidates kept per (query, chunk)
#define NCAND (NCHUNK*CPC) // 128 candidates per query
#define NSEL 24            // exact-rescored candidates per query
#define TPL 6              // per-lane top depth (one class per lane now)
#define QPB 64             // queries per block (4 waves x 16)
#define SBIAS 256.0f       // pre-added to y2 in prep: keys positive -> u32 order ok
#define YTHREADS 200000    // 3125 real tiles x 64 slots
#define PTHREADS 232768    // + 8192 x 4 x-slices
#define ATHREADS 232944    // + 176 y2 pad entries

typedef __attribute__((ext_vector_type(8))) int i32x8;
typedef __attribute__((ext_vector_type(4))) float f32x4;
typedef unsigned int u32;

// ---------------------------------------------------------------------------
// fp32 -> e4m3 via the HW packed converter (1 inst / 2 elems; round-12 SW
// quantizer was ~9 VALU/elem = ~55 us of prep).
// ---------------------------------------------------------------------------
__device__ __forceinline__ u32 pack4_e4m3(float4 v, float sc) {
    u32 w = 0;
    w = __builtin_amdgcn_cvt_pk_fp8_f32(sc * v.x, sc * v.y, w, false);
    w = __builtin_amdgcn_cvt_pk_fp8_f32(sc * v.z, sc * v.w, w, true);
    return w;
}

// ---------------------------------------------------------------------------
// Prep: yt8 = e4m3(y) tile records (2 KB/tile, slot l = g*16+nr: point nr,
// k in [32g,32g+32)) -- serves as the A fragment now (A/B lane maps are
// identical for square MFMA); xb8 = e4m3(-2x) row-major (B fragment);
// y2 = ||y_j||^2 + SBIAS (used directly as the MFMA C operand);
// pads 50000..50175 = FLT_MAX.
// ---------------------------------------------------------------------------
__global__ __launch_bounds__(256) void prep_kernel(
    const float4* __restrict__ x4, const float4* __restrict__ y4,
    u32* __restrict__ xb8, u32* __restrict__ yt8, float* __restrict__ y2) {
    int t = blockIdx.x * 256 + threadIdx.x;
    if (t < YTHREADS) {
        int T = t >> 6, l = t & 63, nr = l & 15, g = l >> 4;
        const float4* src = y4 + ((size_t)(T * 16 + nr) * DIM + g * 32) / 4;
        u32 w[8];
        float ss = 0.f;
        #pragma unroll
        for (int i = 0; i < 8; ++i) {
            float4 v = src[i];
            ss += v.x * v.x + v.y * v.y + v.z * v.z + v.w * v.w;
            w[i] = pack4_e4m3(v, 1.0f);
        }
        uint4* dst = (uint4*)(yt8 + (size_t)T * 512 + l * 8);
        dst[0] = make_uint4(w[0], w[1], w[2], w[3]);
        dst[1] = make_uint4(w[4], w[5], w[6], w[7]);
        ss += __shfl_xor(ss, 16, 64);
        ss += __shfl_xor(ss, 32, 64);
        if (l < 16) y2[T * 16 + l] = ss + SBIAS;
    } else if (t < PTHREADS) {
        int tx = t - YTHREADS, row = tx >> 2, g = tx & 3;
        const float4* src = x4 + ((size_t)row * DIM + g * 32) / 4;
        u32 w[8];
        #pragma unroll
        for (int i = 0; i < 8; ++i) w[i] = pack4_e4m3(src[i], -2.0f);
        uint4* dst = (uint4*)(xb8 + (size_t)row * 32 + g * 8);
        dst[0] = make_uint4(w[0], w[1], w[2], w[3]);
        dst[1] = make_uint4(w[4], w[5], w[6], w[7]);
    } else if (t < ATHREADS) {
        y2[M_PTS + (t - PTHREADS)] = FLT_MAX;   // pad tiles: never selected
    }
}

// ---------------------------------------------------------------------------
// Filter, TRANSPOSED: A = train-point tile, B = 16 queries (read-only -> AGPR
// half), C/D rows = points, cols = queries. A lane's 4 C-values are 4 points
// of ONE query -> a single top-6 list (6 VGPRs, was 4x4=16): total arch-VGPR
// live ~30 fits the 32-reg split at 8 waves/SIMD -> no per-tile accvgpr
// round-trip (the round-5..12 ~50-inst/tile tax). C operand = y2+SBIAS quad
// loaded as float4 (bias/y2 pre-folded in prep). Per tile: 1 MFMA + 3 VMEM +
// ~36 VALU. No LDS/barriers in the loop.
// ---------------------------------------------------------------------------
__global__ __launch_bounds__(256, 8) void knn_filter(
    const u32* __restrict__ xb8, const u32* __restrict__ yt8,
    const float* __restrict__ y2, u32* __restrict__ ckey) {
    const int lane = threadIdx.x & 63;
    const int wid  = threadIdx.x >> 6;      // wave 0..3
    const int g    = lane >> 4;             // point row-group 0..3 (C rows g*4..g*4+3)
    const int nrow = lane & 15;             // query (B col / C col)
    const int chunk = blockIdx.x;           // gridDim.x=16 -> XCD = chunk%8
    const int qb    = blockIdx.y;
    const int qw = qb * QPB + wid * 16;

    // B fragment: query row (qw+nrow), k-slice [32g, 32g+32) -- loop-invariant
    i32x8 bq = *(const i32x8*)(xb8 + (size_t)(qw + nrow) * 32 + g * 8);

    float ts[TPL];
    #pragma unroll
    for (int l = 0; l < TPL; ++l) ts[l] = FLT_MAX;

    const u32* ytp = yt8 + (size_t)chunk * TPC * 512 + lane * 8;
    const f32x4* y2p = (const f32x4*)(y2 + chunk * TPC * 16 + g * 4); // 16B-aligned

    #pragma unroll 4
    for (int t = 0; t < TPC; ++t) {
        i32x8 ay = *(const i32x8*)(ytp + (size_t)t * 512);  // A: 4 point-rows' k-slice
        f32x4 cq = y2p[t * 4];              // y2+SBIAS of points relb..relb+3
        f32x4 d = __builtin_amdgcn_mfma_scale_f32_16x16x128_f8f6f4(
            ay, bq, cq, 0, 0, 0, 0x7F7F7F7F, 0, 0x7F7F7F7F);
        u32 relb = (u32)(t * 16) | (u32)(g * 4);            // 12-bit point index base
        #pragma unroll
        for (int i = 0; i < 4; ++i) {
            float key = __uint_as_float((__float_as_uint(d[i]) & 0xFFFFF000u) | (relb + i));
            float o0 = ts[0], o1 = ts[1], o2 = ts[2], o3 = ts[3], o4 = ts[4];
            ts[0] = fminf(o0, key);
            ts[1] = __builtin_amdgcn_fmed3f(key, o0, o1);
            ts[2] = __builtin_amdgcn_fmed3f(key, o1, o2);
            ts[3] = __builtin_amdgcn_fmed3f(key, o2, o3);
            ts[4] = __builtin_amdgcn_fmed3f(key, o3, o4);
            ts[5] = __builtin_amdgcn_fmed3f(key, o4, ts[5]);
        }
    }

    // ---- merge 4 row-group classes -> per-query sorted top-8 ----
    __shared__ u32 smem[QPB * 25];          // 64 q x (24 keys + pad) = 6.4 KB
    {
        int ql = wid * 16 + nrow;
        #pragma unroll
        for (int l = 0; l < TPL; ++l)
            smem[ql * 25 + g * TPL + l] = __float_as_uint(ts[l]);
    }
    __syncthreads();
    if (threadIdx.x < QPB) {
        int ql = threadIdx.x;
        float bs[CPC];
        #pragma unroll
        for (int i = 0; i < CPC; ++i) bs[i] = FLT_MAX;
        for (int e = 0; e < 4 * TPL; ++e) {
            float f = __uint_as_float(smem[ql * 25 + e]);
            #pragma unroll
            for (int q2 = 0; q2 < CPC; ++q2) {
                float mn = fminf(bs[q2], f);
                f = fmaxf(bs[q2], f);
                bs[q2] = mn;
            }
        }
        u32* dst = ckey + ((size_t)(qb * QPB + ql) * NCHUNK + chunk) * CPC;
        #pragma unroll
        for (int i = 0; i < CPC; ++i) dst[i] = __float_as_uint(bs[i]);
    }
}

// ---------------------------------------------------------------------------
// Finalize (unchanged from round 12): 8 queries/block, half-wave per query.
// Parallel exact-rank select over the 128 positive keys (u32 compare valid);
// exact fp64 rescore one cand/sub-lane; serial top-10 + vote on sub-lane 0
// ((score,idx) tie = jax top_k; class ties -> LARGEST label).
// ---------------------------------------------------------------------------
__global__ __launch_bounds__(256) void knn_finalize(
    const u32* __restrict__ ckey, const float* __restrict__ x,
    const float* __restrict__ y, const int* __restrict__ labels,
    int* __restrict__ out) {
    const int lane = threadIdx.x & 63;
    const int wid  = threadIdx.x >> 6;
    const int qbase = blockIdx.x * 8;
    const int ql = wid * 2 + (lane >> 5);   // query-in-block 0..7
    const int sl = lane & 31;               // sub-lane in half-wave

    __shared__ u32 skey[8][NCAND];
    __shared__ int sidx[8][NSEL];
    __shared__ double sex[8][NSEL];

    for (int i = threadIdx.x; i < 8 * NCAND; i += 256)
        skey[i >> 7][i & 127] = ckey[(size_t)(qbase + (i >> 7)) * NCAND + (i & 127)];
    __syncthreads();

    {
        u32 ke[4];
        int rank[4];
        #pragma unroll
        for (int r0 = 0; r0 < 4; ++r0) {
            ke[r0] = skey[ql][r0 * 32 + sl];
            rank[r0] = 0;
        }
        for (int j = 0; j < NCAND; ++j) {
            u32 kj = skey[ql][j];
            #pragma unroll
            for (int r0 = 0; r0 < 4; ++r0)
                rank[r0] += (kj < ke[r0] || (kj == ke[r0] && j < r0 * 32 + sl)) ? 1 : 0;
        }
        #pragma unroll
        for (int r0 = 0; r0 < 4; ++r0) {
            if (rank[r0] < NSEL) {
                int e = r0 * 32 + sl;
                sidx[ql][rank[r0]] = (e >> 3) * (TPC * 16) + (int)(ke[r0] & 0xFFFu);
            }
        }
    }
    __syncthreads();

    if (sl < NSEL) {
        const int idx = sidx[ql][sl];
        const float4* xr = (const float4*)(x + (size_t)(qbase + ql) * DIM);
        const float4* yr = (const float4*)(y + (size_t)idx * DIM);
        double dy2 = 0.0, dxy = 0.0;
        #pragma unroll 8
        for (int i = 0; i < 32; ++i) {
            float4 yv = yr[i];
            float4 xv = xr[i];
            dy2 = fma((double)yv.x, (double)yv.x, dy2);
            dy2 = fma((double)yv.y, (double)yv.y, dy2);
            dy2 = fma((double)yv.z, (double)yv.z, dy2);
            dy2 = fma((double)yv.w, (double)yv.w, dy2);
            dxy = fma((double)xv.x, (double)yv.x, dxy);
            dxy = fma((double)xv.y, (double)yv.y, dxy);
            dxy = fma((double)xv.z, (double)yv.z, dxy);
            dxy = fma((double)xv.w, (double)yv.w, dxy);
        }
        sex[ql][sl] = dy2 - 2.0 * dxy;
    }
    __syncthreads();

    if (sl == 0) {
        double tsv[KNN]; int ti[KNN];
        #pragma unroll
        for (int i = 0; i < KNN; ++i) { tsv[i] = 1e300; ti[i] = INT_MAX; }
        #pragma unroll
        for (int c = 0; c < NSEL; ++c) {
            double s = sex[ql][c];
            int id = sidx[ql][c];
            #pragma unroll
            for (int pp = 0; pp < KNN; ++pp) {
                bool lt = (s < tsv[pp]) || (s == tsv[pp] && id < ti[pp]);
                double ns = lt ? tsv[pp] : s;  int nid = lt ? ti[pp] : id;
                tsv[pp] = lt ? s : tsv[pp];    ti[pp] = lt ? id : ti[pp];
                s = ns; id = nid;
            }
        }
        int lab[KNN];
        #pragma unroll
        for (int i = 0; i < KNN; ++i) lab[i] = labels[ti[i]];
        int bestc = 0, bestn = -1;
        #pragma unroll
        for (int c = 0; c < NCLS; ++c) {
            int n = 0;
            #pragma unroll
            for (int i = 0; i < KNN; ++i) n += (lab[i] == c) ? 1 : 0;
            if (n >= bestn) { bestn = n; bestc = c; }   // >= : ties -> larger label
        }
        out[qbase + ql] = bestc;
    }
}

// ---------------------------------------------------------------------------
extern "C" void kernel_launch(void* const* d_in, const int* in_sizes, int n_in,
                              void* d_out, int out_size, void* d_ws, size_t ws_size,
                              hipStream_t stream) {
    const float* x      = (const float*)d_in[0];
    const float* y      = (const float*)d_in[1];
    const int*   labels = (const int*)d_in[2];
    // d_in[3] is k == 10, baked in.

    char* ws = (char*)d_ws;
    size_t off = 0;
    u32* xb8 = (u32*)(ws + off);    off += (size_t)N_Q * DIM;            //  1.05 MB
    u32* yt8 = (u32*)(ws + off);    off += (size_t)NCHUNK * TPC * 2048;  //  6.42 MB
    float* y2 = (float*)(ws + off); off += (size_t)NCHUNK * TPC * 16 * 4;//  0.20 MB
    u32* ckey = (u32*)(ws + off);   off += (size_t)N_Q * NCAND * 4;      //  4.19 MB
    int* out = (int*)d_out;

    prep_kernel<<<(ATHREADS + 255) / 256, 256, 0, stream>>>(
        (const float4*)x, (const float4*)y, xb8, yt8, y2);
    knn_filter<<<dim3(NCHUNK, N_Q / QPB), 256, 0, stream>>>(xb8, yt8, y2, ckey);
    knn_finalize<<<N_Q / 8, 256, 0, stream>>>(ckey, x, y, labels, out);
}

// Round 14
// 274.011 us; speedup vs baseline: 1.0352x; 1.0352x over previous
//
#include <hip/hip_runtime.h>
#include <float.h>
#include <limits.h>

#define N_Q 8192
#define M_PTS 50000
#define DIM 128
#define KNN 10
#define NCLS 10
#define NCHUNK 16          // 16 chunks x 196 tiles (3136 tiles, 11 padded)
#define TPC 196            // tiles per chunk (uniform, compile-time)
#define CPC 8              // candidates kept per (query, chunk)
#define NCAND (NCHUNK*CPC) // 128 candidates per query
#define NSEL 24            // exact-rescored candidates per query
#define TPL 6              // per-(lane,query) top depth
#define QPB 128            // queries per block (4 waves x 32)
#define SBIAS 256.0f       // pre-added to y2: keys positive -> u32 order == float order
#define YTHREADS 200000    // 3125 real tiles x 64 slots
#define PTHREADS 232768    // + 8192 x 4 x-slices
#define ATHREADS 232944    // + 176 y2 pad entries

typedef __attribute__((ext_vector_type(8))) int i32x8;
typedef __attribute__((ext_vector_type(4))) float f32x4;
typedef unsigned int u32;

// ---------------------------------------------------------------------------
// fp32 -> e4m3 via the HW packed converter.
// ---------------------------------------------------------------------------
__device__ __forceinline__ u32 pack4_e4m3(float4 v, float sc) {
    u32 w = 0;
    w = __builtin_amdgcn_cvt_pk_fp8_f32(sc * v.x, sc * v.y, w, false);
    w = __builtin_amdgcn_cvt_pk_fp8_f32(sc * v.z, sc * v.w, w, true);
    return w;
}

// ---------------------------------------------------------------------------
// Prep: yt8 = e4m3(y) tile records (2 KB/tile, slot l = g*16+nr: point nr,
// k in [32g,32g+32)) = the A fragment; xb8 = e4m3(-2x) row-major (B);
// y2 = ||y_j||^2 + SBIAS (direct MFMA C operand); pads = FLT_MAX.
// ---------------------------------------------------------------------------
__global__ __launch_bounds__(256) void prep_kernel(
    const float4* __restrict__ x4, const float4* __restrict__ y4,
    u32* __restrict__ xb8, u32* __restrict__ yt8, float* __restrict__ y2) {
    int t = blockIdx.x * 256 + threadIdx.x;
    if (t < YTHREADS) {
        int T = t >> 6, l = t & 63, nr = l & 15, g = l >> 4;
        const float4* src = y4 + ((size_t)(T * 16 + nr) * DIM + g * 32) / 4;
        u32 w[8];
        float ss = 0.f;
        #pragma unroll
        for (int i = 0; i < 8; ++i) {
            float4 v = src[i];
            ss += v.x * v.x + v.y * v.y + v.z * v.z + v.w * v.w;
            w[i] = pack4_e4m3(v, 1.0f);
        }
        uint4* dst = (uint4*)(yt8 + (size_t)T * 512 + l * 8);
        dst[0] = make_uint4(w[0], w[1], w[2], w[3]);
        dst[1] = make_uint4(w[4], w[5], w[6], w[7]);
        ss += __shfl_xor(ss, 16, 64);
        ss += __shfl_xor(ss, 32, 64);
        if (l < 16) y2[T * 16 + l] = ss + SBIAS;
    } else if (t < PTHREADS) {
        int tx = t - YTHREADS, row = tx >> 2, g = tx & 3;
        const float4* src = x4 + ((size_t)row * DIM + g * 32) / 4;
        u32 w[8];
        #pragma unroll
        for (int i = 0; i < 8; ++i) w[i] = pack4_e4m3(src[i], -2.0f);
        uint4* dst = (uint4*)(xb8 + (size_t)row * 32 + g * 8);
        dst[0] = make_uint4(w[0], w[1], w[2], w[3]);
        dst[1] = make_uint4(w[4], w[5], w[6], w[7]);
    } else if (t < ATHREADS) {
        y2[M_PTS + (t - PTHREADS)] = FLT_MAX;   // pad tiles: never selected
    }
}

// ---------------------------------------------------------------------------
// Filter, transposed fp8 with TWO query-sets per wave: A = train-point tile
// (one 2 KB load), B = two loop-invariant query fragments -> each tile load
// feeds 2 MFMAs / 8 scores. This is the L2-bandwidth lever: B-stream traffic
// is 1.6 GB (round-12/13's 1-set streamed 3.2 GB at ~22 TB/s = ~65% of the
// 34.5 TB/s L2 ceiling -- the invariant wall). Two independent ts chains
// (one per set) keep insert latency pipelined. C operand = y2+SBIAS float4.
// Per tile: 2 MFMA + 3 VMEM + ~64 VALU. Grid 16x64 = 1024 = 4 blocks/CU.
// ---------------------------------------------------------------------------
__global__ __launch_bounds__(256, 4) void knn_filter(
    const u32* __restrict__ xb8, const u32* __restrict__ yt8,
    const float* __restrict__ y2, u32* __restrict__ ckey) {
    const int lane = threadIdx.x & 63;
    const int wid  = threadIdx.x >> 6;      // wave 0..3
    const int g    = lane >> 4;             // point row-group (C rows g*4..g*4+3)
    const int nrow = lane & 15;             // query within set (B col / C col)
    const int chunk = blockIdx.x;           // gridDim.x=16 -> XCD = chunk%8
    const int qb    = blockIdx.y;
    const int qw = qb * QPB + wid * 32;

    // B fragments: two query-sets, k-slice [32g, 32g+32) -- loop-invariant
    i32x8 bq0 = *(const i32x8*)(xb8 + (size_t)(qw + nrow) * 32 + g * 8);
    i32x8 bq1 = *(const i32x8*)(xb8 + (size_t)(qw + 16 + nrow) * 32 + g * 8);

    float ts0[TPL], ts1[TPL];
    #pragma unroll
    for (int l = 0; l < TPL; ++l) { ts0[l] = FLT_MAX; ts1[l] = FLT_MAX; }

    const u32* ytp = yt8 + (size_t)chunk * TPC * 512 + lane * 8;
    const f32x4* y2p = (const f32x4*)(y2 + chunk * TPC * 16 + g * 4);

    #pragma unroll 2
    for (int t = 0; t < TPC; ++t) {
        i32x8 ay = *(const i32x8*)(ytp + (size_t)t * 512);  // 4 point-rows' k-slice
        f32x4 cq = y2p[t * 4];              // y2+SBIAS of points relb..relb+3
        f32x4 d0 = __builtin_amdgcn_mfma_scale_f32_16x16x128_f8f6f4(
            ay, bq0, cq, 0, 0, 0, 0x7F7F7F7F, 0, 0x7F7F7F7F);
        f32x4 d1 = __builtin_amdgcn_mfma_scale_f32_16x16x128_f8f6f4(
            ay, bq1, cq, 0, 0, 0, 0x7F7F7F7F, 0, 0x7F7F7F7F);
        u32 relb = (u32)(t * 16) | (u32)(g * 4);            // 12-bit point base
        #pragma unroll
        for (int i = 0; i < 4; ++i) {       // two independent insert chains
            float k0 = __uint_as_float((__float_as_uint(d0[i]) & 0xFFFFF000u) | (relb + i));
            float k1 = __uint_as_float((__float_as_uint(d1[i]) & 0xFFFFF000u) | (relb + i));
            float a0 = ts0[0], a1 = ts0[1], a2 = ts0[2], a3 = ts0[3], a4 = ts0[4];
            float b0 = ts1[0], b1 = ts1[1], b2 = ts1[2], b3 = ts1[3], b4 = ts1[4];
            ts0[0] = fminf(a0, k0);
            ts1[0] = fminf(b0, k1);
            ts0[1] = __builtin_amdgcn_fmed3f(k0, a0, a1);
            ts1[1] = __builtin_amdgcn_fmed3f(k1, b0, b1);
            ts0[2] = __builtin_amdgcn_fmed3f(k0, a1, a2);
            ts1[2] = __builtin_amdgcn_fmed3f(k1, b1, b2);
            ts0[3] = __builtin_amdgcn_fmed3f(k0, a2, a3);
            ts1[3] = __builtin_amdgcn_fmed3f(k1, b2, b3);
            ts0[4] = __builtin_amdgcn_fmed3f(k0, a3, a4);
            ts1[4] = __builtin_amdgcn_fmed3f(k1, b3, b4);
            ts0[5] = __builtin_amdgcn_fmed3f(k0, a4, ts0[5]);
            ts1[5] = __builtin_amdgcn_fmed3f(k1, b4, ts1[5]);
        }
    }

    // ---- merge 4 row-group classes x 2 sets -> per-query sorted top-8 ----
    __shared__ u32 smem[QPB * 25];          // 128 q x (24 keys + pad) = 12.8 KB
    {
        int ql0 = wid * 32 + nrow;
        int ql1 = wid * 32 + 16 + nrow;
        #pragma unroll
        for (int l = 0; l < TPL; ++l) {
            smem[ql0 * 25 + g * TPL + l] = __float_as_uint(ts0[l]);
            smem[ql1 * 25 + g * TPL + l] = __float_as_uint(ts1[l]);
        }
    }
    __syncthreads();
    if (threadIdx.x < QPB) {
        int ql = threadIdx.x;
        float bs[CPC];
        #pragma unroll
        for (int i = 0; i < CPC; ++i) bs[i] = FLT_MAX;
        for (int e = 0; e < 4 * TPL; ++e) {
            float f = __uint_as_float(smem[ql * 25 + e]);
            #pragma unroll
            for (int q2 = 0; q2 < CPC; ++q2) {
                float mn = fminf(bs[q2], f);
                f = fmaxf(bs[q2], f);
                bs[q2] = mn;
            }
        }
        u32* dst = ckey + ((size_t)(qb * QPB + ql) * NCHUNK + chunk) * CPC;
        #pragma unroll
        for (int i = 0; i < CPC; ++i) dst[i] = __float_as_uint(bs[i]);
    }
}

// ---------------------------------------------------------------------------
// Finalize (unchanged, verified): 8 queries/block, half-wave per query.
// Parallel exact-rank select over the 128 positive keys (u32 compare valid);
// exact fp64 rescore one cand/sub-lane; serial top-10 + vote on sub-lane 0
// ((score,idx) tie = jax top_k; class ties -> LARGEST label).
// ---------------------------------------------------------------------------
__global__ __launch_bounds__(256) void knn_finalize(
    const u32* __restrict__ ckey, const float* __restrict__ x,
    const float* __restrict__ y, const int* __restrict__ labels,
    int* __restrict__ out) {
    const int lane = threadIdx.x & 63;
    const int wid  = threadIdx.x >> 6;
    const int qbase = blockIdx.x * 8;
    const int ql = wid * 2 + (lane >> 5);   // query-in-block 0..7
    const int sl = lane & 31;               // sub-lane in half-wave

    __shared__ u32 skey[8][NCAND];
    __shared__ int sidx[8][NSEL];
    __shared__ double sex[8][NSEL];

    for (int i = threadIdx.x; i < 8 * NCAND; i += 256)
        skey[i >> 7][i & 127] = ckey[(size_t)(qbase + (i >> 7)) * NCAND + (i & 127)];
    __syncthreads();

    {
        u32 ke[4];
        int rank[4];
        #pragma unroll
        for (int r0 = 0; r0 < 4; ++r0) {
            ke[r0] = skey[ql][r0 * 32 + sl];
            rank[r0] = 0;
        }
        for (int j = 0; j < NCAND; ++j) {
            u32 kj = skey[ql][j];
            #pragma unroll
            for (int r0 = 0; r0 < 4; ++r0)
                rank[r0] += (kj < ke[r0] || (kj == ke[r0] && j < r0 * 32 + sl)) ? 1 : 0;
        }
        #pragma unroll
        for (int r0 = 0; r0 < 4; ++r0) {
            if (rank[r0] < NSEL) {
                int e = r0 * 32 + sl;
                sidx[ql][rank[r0]] = (e >> 3) * (TPC * 16) + (int)(ke[r0] & 0xFFFu);
            }
        }
    }
    __syncthreads();

    if (sl < NSEL) {
        const int idx = sidx[ql][sl];
        const float4* xr = (const float4*)(x + (size_t)(qbase + ql) * DIM);
        const float4* yr = (const float4*)(y + (size_t)idx * DIM);
        double dy2 = 0.0, dxy = 0.0;
        #pragma unroll 8
        for (int i = 0; i < 32; ++i) {
            float4 yv = yr[i];
            float4 xv = xr[i];
            dy2 = fma((double)yv.x, (double)yv.x, dy2);
            dy2 = fma((double)yv.y, (double)yv.y, dy2);
            dy2 = fma((double)yv.z, (double)yv.z, dy2);
            dy2 = fma((double)yv.w, (double)yv.w, dy2);
            dxy = fma((double)xv.x, (double)yv.x, dxy);
            dxy = fma((double)xv.y, (double)yv.y, dxy);
            dxy = fma((double)xv.z, (double)yv.z, dxy);
            dxy = fma((double)xv.w, (double)yv.w, dxy);
        }
        sex[ql][sl] = dy2 - 2.0 * dxy;
    }
    __syncthreads();

    if (sl == 0) {
        double tsv[KNN]; int ti[KNN];
        #pragma unroll
        for (int i = 0; i < KNN; ++i) { tsv[i] = 1e300; ti[i] = INT_MAX; }
        #pragma unroll
        for (int c = 0; c < NSEL; ++c) {
            double s = sex[ql][c];
            int id = sidx[ql][c];
            #pragma unroll
            for (int pp = 0; pp < KNN; ++pp) {
                bool lt = (s < tsv[pp]) || (s == tsv[pp] && id < ti[pp]);
                double ns = lt ? tsv[pp] : s;  int nid = lt ? ti[pp] : id;
                tsv[pp] = lt ? s : tsv[pp];    ti[pp] = lt ? id : ti[pp];
                s = ns; id = nid;
            }
        }
        int lab[KNN];
        #pragma unroll
        for (int i = 0; i < KNN; ++i) lab[i] = labels[ti[i]];
        int bestc = 0, bestn = -1;
        #pragma unroll
        for (int c = 0; c < NCLS; ++c) {
            int n = 0;
            #pragma unroll
            for (int i = 0; i < KNN; ++i) n += (lab[i] == c) ? 1 : 0;
            if (n >= bestn) { bestn = n; bestc = c; }   // >= : ties -> larger label
        }
        out[qbase + ql] = bestc;
    }
}

// ---------------------------------------------------------------------------
extern "C" void kernel_launch(void* const* d_in, const int* in_sizes, int n_in,
                              void* d_out, int out_size, void* d_ws, size_t ws_size,
                              hipStream_t stream) {
    const float* x      = (const float*)d_in[0];
    const float* y      = (const float*)d_in[1];
    const int*   labels = (const int*)d_in[2];
    // d_in[3] is k == 10, baked in.

    char* ws = (char*)d_ws;
    size_t off = 0;
    u32* xb8 = (u32*)(ws + off);    off += (size_t)N_Q * DIM;            //  1.05 MB
    u32* yt8 = (u32*)(ws + off);    off += (size_t)NCHUNK * TPC * 2048;  //  6.42 MB
    float* y2 = (float*)(ws + off); off += (size_t)NCHUNK * TPC * 16 * 4;//  0.20 MB
    u32* ckey = (u32*)(ws + off);   off += (size_t)N_Q * NCAND * 4;      //  4.19 MB
    int* out = (int*)d_out;

    prep_kernel<<<(ATHREADS + 255) / 256, 256, 0, stream>>>(
        (const float4*)x, (const float4*)y, xb8, yt8, y2);
    knn_filter<<<dim3(NCHUNK, N_Q / QPB), 256, 0, stream>>>(xb8, yt8, y2, ckey);
    knn_finalize<<<N_Q / 8, 256, 0, stream>>>(ckey, x, y, labels, out);
}

// Round 15
// 268.224 us; speedup vs baseline: 1.0575x; 1.0216x over previous
//
#include <hip/hip_runtime.h>
#include <float.h>
#include <limits.h>

#define N_Q 8192
#define M_PTS 50000
#define DIM 128
#define KNN 10
#define NCLS 10
#define NCHUNK 16          // 16 chunks x 196 tiles (3136 tiles, 11 padded)
#define TPC 196            // tiles per chunk (uniform, compile-time)
#define CPC 8              // candidates kept per (query, chunk)
#define NCAND (NCHUNK*CPC) // 128 candidates per query
#define NSEL 24            // exact-rescored candidates per query
#define TPL 6              // per-(lane,query) top depth
#define QPB 128            // queries per block (4 waves x 32)
#define SBIAS 256.0f       // pre-added to y2: keys positive -> u32 order == float order
#define XN4 (N_Q*DIM/4)    // 262144 float4 in x
#define YN4 (M_PTS*DIM/4)  // 1600000 float4 in y

typedef __attribute__((ext_vector_type(8))) int i32x8;
typedef __attribute__((ext_vector_type(4))) float f32x4;
typedef unsigned int u32;

// ---------------------------------------------------------------------------
// fp32 -> e4m3 via the HW packed converter.
// ---------------------------------------------------------------------------
__device__ __forceinline__ u32 pack4_e4m3(float4 v, float sc) {
    u32 w = 0;
    w = __builtin_amdgcn_cvt_pk_fp8_f32(sc * v.x, sc * v.y, w, false);
    w = __builtin_amdgcn_cvt_pk_fp8_f32(sc * v.z, sc * v.w, w, true);
    return w;
}

// ---------------------------------------------------------------------------
// Prep, COALESCED (rounds 10-14 read y with 512-B-stride per thread): one
// float4 per thread, consecutive threads = consecutive addresses. Packed u32
// scatter-written into the tile-record layout (32-B segments, L1-absorbed).
// yt8 record: u32[T*512 + (g*16+nr)*8 + s] = elems (k = 32g+4s..) of point
// (T*16+nr). y2 = ||y_j||^2 + SBIAS (direct MFMA C operand); pads FLT_MAX.
// ---------------------------------------------------------------------------
__global__ __launch_bounds__(256) void prep_kernel(
    const float4* __restrict__ x4, const float4* __restrict__ y4,
    u32* __restrict__ xb8, u32* __restrict__ yt8, float* __restrict__ y2) {
    int t = blockIdx.x * 256 + threadIdx.x;
    if (t < XN4) {
        xb8[t] = pack4_e4m3(x4[t], -2.0f);  // row-major: u32 idx == t
    } else if (t < XN4 + YN4) {
        int j = t - XN4;                    // float4 index into y
        int row = j >> 5;                   // point 0..49999
        int d4  = j & 31;                   // which float4 of the row
        float4 v = y4[j];
        u32 w = pack4_e4m3(v, 1.0f);
        int T = row >> 4, nr = row & 15;
        int g2 = d4 >> 3, s = d4 & 7;
        yt8[(size_t)T * 512 + (g2 * 16 + nr) * 8 + s] = w;
        float p = v.x * v.x + v.y * v.y + v.z * v.z + v.w * v.w;
        #pragma unroll
        for (int off = 16; off > 0; off >>= 1) p += __shfl_xor(p, off, 64);
        if (d4 == 0) y2[row] = p + SBIAS;
    } else if (t < XN4 + YN4 + 176) {
        y2[M_PTS + (t - XN4 - YN4)] = FLT_MAX;   // pad tiles: never selected
    }
}

// ---------------------------------------------------------------------------
// Filter: transposed fp8 (A = train tile, B = two loop-invariant query sets)
// with EXPLICIT 2-DEEP PREFETCH ROTATION: tiles t+2/t+3 are requested before
// processing t/t+1, whose data was requested one full loop body earlier --
// rounds 10-14 consumed each load immediately after issue (zero prefetch
// distance -> full L2-under-load latency ~500-900 cyc per iteration, the
// invariant ~150 us wall). C operand = y2+SBIAS float4. Per tile: 2 MFMA +
// 3 VMEM + ~64 VALU. Grid 16x64 = 1024 = 4 blocks/CU.
// ---------------------------------------------------------------------------
__global__ __launch_bounds__(256, 4) void knn_filter(
    const u32* __restrict__ xb8, const u32* __restrict__ yt8,
    const float* __restrict__ y2, u32* __restrict__ ckey) {
    const int lane = threadIdx.x & 63;
    const int wid  = threadIdx.x >> 6;      // wave 0..3
    const int g    = lane >> 4;             // point row-group (C rows g*4..g*4+3)
    const int nrow = lane & 15;             // query within set (B col / C col)
    const int chunk = blockIdx.x;           // gridDim.x=16 -> XCD = chunk%8
    const int qb    = blockIdx.y;
    const int qw = qb * QPB + wid * 32;

    // B fragments: two query-sets, k-slice [32g, 32g+32) -- loop-invariant
    i32x8 bq0 = *(const i32x8*)(xb8 + (size_t)(qw + nrow) * 32 + g * 8);
    i32x8 bq1 = *(const i32x8*)(xb8 + (size_t)(qw + 16 + nrow) * 32 + g * 8);

    float ts0[TPL], ts1[TPL];
    #pragma unroll
    for (int l = 0; l < TPL; ++l) { ts0[l] = FLT_MAX; ts1[l] = FLT_MAX; }

    const u32* ytp = yt8 + (size_t)chunk * TPC * 512 + lane * 8;
    const f32x4* y2p = (const f32x4*)(y2 + chunk * TPC * 16 + g * 4);

    auto process = [&](i32x8 ay, f32x4 cq, int t) {
        f32x4 d0 = __builtin_amdgcn_mfma_scale_f32_16x16x128_f8f6f4(
            ay, bq0, cq, 0, 0, 0, 0x7F7F7F7F, 0, 0x7F7F7F7F);
        f32x4 d1 = __builtin_amdgcn_mfma_scale_f32_16x16x128_f8f6f4(
            ay, bq1, cq, 0, 0, 0, 0x7F7F7F7F, 0, 0x7F7F7F7F);
        u32 relb = (u32)(t * 16) | (u32)(g * 4);        // 12-bit point base
        #pragma unroll
        for (int i = 0; i < 4; ++i) {       // two independent insert chains
            float k0 = __uint_as_float((__float_as_uint(d0[i]) & 0xFFFFF000u) | (relb + i));
            float k1 = __uint_as_float((__float_as_uint(d1[i]) & 0xFFFFF000u) | (relb + i));
            float a0 = ts0[0], a1 = ts0[1], a2 = ts0[2], a3 = ts0[3], a4 = ts0[4];
            float b0 = ts1[0], b1 = ts1[1], b2 = ts1[2], b3 = ts1[3], b4 = ts1[4];
            ts0[0] = fminf(a0, k0);
            ts1[0] = fminf(b0, k1);
            ts0[1] = __builtin_amdgcn_fmed3f(k0, a0, a1);
            ts1[1] = __builtin_amdgcn_fmed3f(k1, b0, b1);
            ts0[2] = __builtin_amdgcn_fmed3f(k0, a1, a2);
            ts1[2] = __builtin_amdgcn_fmed3f(k1, b1, b2);
            ts0[3] = __builtin_amdgcn_fmed3f(k0, a2, a3);
            ts1[3] = __builtin_amdgcn_fmed3f(k1, b2, b3);
            ts0[4] = __builtin_amdgcn_fmed3f(k0, a3, a4);
            ts1[4] = __builtin_amdgcn_fmed3f(k1, b3, b4);
            ts0[5] = __builtin_amdgcn_fmed3f(k0, a4, ts0[5]);
            ts1[5] = __builtin_amdgcn_fmed3f(k1, b4, ts1[5]);
        }
    };

    // prologue: tiles 0 and 1 in flight
    i32x8 ayA = *(const i32x8*)(ytp);
    i32x8 ayB = *(const i32x8*)(ytp + 512);
    f32x4 cqA = y2p[0];
    f32x4 cqB = y2p[4];

    int t = 0;
    for (; t < TPC - 2; t += 2) {
        i32x8 nA = *(const i32x8*)(ytp + (size_t)(t + 2) * 512);  // prefetch t+2
        f32x4 pA = y2p[(t + 2) * 4];
        process(ayA, cqA, t);
        ayA = nA; cqA = pA;
        i32x8 nB = *(const i32x8*)(ytp + (size_t)(t + 3) * 512);  // prefetch t+3
        f32x4 pB = y2p[(t + 3) * 4];
        process(ayB, cqB, t + 1);
        ayB = nB; cqB = pB;
    }
    process(ayA, cqA, TPC - 2);
    process(ayB, cqB, TPC - 1);

    // ---- merge 4 row-group classes x 2 sets -> per-query sorted top-8 ----
    __shared__ u32 smem[QPB * 25];          // 12.8 KB
    {
        int ql0 = wid * 32 + nrow;
        int ql1 = wid * 32 + 16 + nrow;
        #pragma unroll
        for (int l = 0; l < TPL; ++l) {
            smem[ql0 * 25 + g * TPL + l] = __float_as_uint(ts0[l]);
            smem[ql1 * 25 + g * TPL + l] = __float_as_uint(ts1[l]);
        }
    }
    __syncthreads();
    if (threadIdx.x < QPB) {
        int ql = threadIdx.x;
        float bs[CPC];
        #pragma unroll
        for (int i = 0; i < CPC; ++i) bs[i] = FLT_MAX;
        for (int e = 0; e < 4 * TPL; ++e) {
            float f = __uint_as_float(smem[ql * 25 + e]);
            #pragma unroll
            for (int q2 = 0; q2 < CPC; ++q2) {
                float mn = fminf(bs[q2], f);
                f = fmaxf(bs[q2], f);
                bs[q2] = mn;
            }
        }
        u32* dst = ckey + ((size_t)(qb * QPB + ql) * NCHUNK + chunk) * CPC;
        #pragma unroll
        for (int i = 0; i < CPC; ++i) dst[i] = __float_as_uint(bs[i]);
    }
}

// ---------------------------------------------------------------------------
// Finalize (unchanged, verified): 8 queries/block, half-wave per query.
// Parallel exact-rank select over the 128 positive keys (u32 compare valid);
// exact fp64 rescore one cand/sub-lane; serial top-10 + vote on sub-lane 0
// ((score,idx) tie = jax top_k; class ties -> LARGEST label).
// ---------------------------------------------------------------------------
__global__ __launch_bounds__(256) void knn_finalize(
    const u32* __restrict__ ckey, const float* __restrict__ x,
    const float* __restrict__ y, const int* __restrict__ labels,
    int* __restrict__ out) {
    const int lane = threadIdx.x & 63;
    const int wid  = threadIdx.x >> 6;
    const int qbase = blockIdx.x * 8;
    const int ql = wid * 2 + (lane >> 5);   // query-in-block 0..7
    const int sl = lane & 31;               // sub-lane in half-wave

    __shared__ u32 skey[8][NCAND];
    __shared__ int sidx[8][NSEL];
    __shared__ double sex[8][NSEL];

    for (int i = threadIdx.x; i < 8 * NCAND; i += 256)
        skey[i >> 7][i & 127] = ckey[(size_t)(qbase + (i >> 7)) * NCAND + (i & 127)];
    __syncthreads();

    {
        u32 ke[4];
        int rank[4];
        #pragma unroll
        for (int r0 = 0; r0 < 4; ++r0) {
            ke[r0] = skey[ql][r0 * 32 + sl];
            rank[r0] = 0;
        }
        for (int j = 0; j < NCAND; ++j) {
            u32 kj = skey[ql][j];
            #pragma unroll
            for (int r0 = 0; r0 < 4; ++r0)
                rank[r0] += (kj < ke[r0] || (kj == ke[r0] && j < r0 * 32 + sl)) ? 1 : 0;
        }
        #pragma unroll
        for (int r0 = 0; r0 < 4; ++r0) {
            if (rank[r0] < NSEL) {
                int e = r0 * 32 + sl;
                sidx[ql][rank[r0]] = (e >> 3) * (TPC * 16) + (int)(ke[r0] & 0xFFFu);
            }
        }
    }
    __syncthreads();

    if (sl < NSEL) {
        const int idx = sidx[ql][sl];
        const float4* xr = (const float4*)(x + (size_t)(qbase + ql) * DIM);
        const float4* yr = (const float4*)(y + (size_t)idx * DIM);
        double dy2 = 0.0, dxy = 0.0;
        #pragma unroll 8
        for (int i = 0; i < 32; ++i) {
            float4 yv = yr[i];
            float4 xv = xr[i];
            dy2 = fma((double)yv.x, (double)yv.x, dy2);
            dy2 = fma((double)yv.y, (double)yv.y, dy2);
            dy2 = fma((double)yv.z, (double)yv.z, dy2);
            dy2 = fma((double)yv.w, (double)yv.w, dy2);
            dxy = fma((double)xv.x, (double)yv.x, dxy);
            dxy = fma((double)xv.y, (double)yv.y, dxy);
            dxy = fma((double)xv.z, (double)yv.z, dxy);
            dxy = fma((double)xv.w, (double)yv.w, dxy);
        }
        sex[ql][sl] = dy2 - 2.0 * dxy;
    }
    __syncthreads();

    if (sl == 0) {
        double tsv[KNN]; int ti[KNN];
        #pragma unroll
        for (int i = 0; i < KNN; ++i) { tsv[i] = 1e300; ti[i] = INT_MAX; }
        #pragma unroll
        for (int c = 0; c < NSEL; ++c) {
            double s = sex[ql][c];
            int id = sidx[ql][c];
            #pragma unroll
            for (int pp = 0; pp < KNN; ++pp) {
                bool lt = (s < tsv[pp]) || (s == tsv[pp] && id < ti[pp]);
                double ns = lt ? tsv[pp] : s;  int nid = lt ? ti[pp] : id;
                tsv[pp] = lt ? s : tsv[pp];    ti[pp] = lt ? id : ti[pp];
                s = ns; id = nid;
            }
        }
        int lab[KNN];
        #pragma unroll
        for (int i = 0; i < KNN; ++i) lab[i] = labels[ti[i]];
        int bestc = 0, bestn = -1;
        #pragma unroll
        for (int c = 0; c < NCLS; ++c) {
            int n = 0;
            #pragma unroll
            for (int i = 0; i < KNN; ++i) n += (lab[i] == c) ? 1 : 0;
            if (n >= bestn) { bestn = n; bestc = c; }   // >= : ties -> larger label
        }
        out[qbase + ql] = bestc;
    }
}

// ---------------------------------------------------------------------------
extern "C" void kernel_launch(void* const* d_in, const int* in_sizes, int n_in,
                              void* d_out, int out_size, void* d_ws, size_t ws_size,
                              hipStream_t stream) {
    const float* x      = (const float*)d_in[0];
    const float* y      = (const float*)d_in[1];
    const int*   labels = (const int*)d_in[2];
    // d_in[3] is k == 10, baked in.

    char* ws = (char*)d_ws;
    size_t off = 0;
    u32* xb8 = (u32*)(ws + off);    off += (size_t)N_Q * DIM;            //  1.05 MB
    u32* yt8 = (u32*)(ws + off);    off += (size_t)NCHUNK * TPC * 2048;  //  6.42 MB
    float* y2 = (float*)(ws + off); off += (size_t)NCHUNK * TPC * 16 * 4;//  0.20 MB
    u32* ckey = (u32*)(ws + off);   off += (size_t)N_Q * NCAND * 4;      //  4.19 MB
    int* out = (int*)d_out;

    prep_kernel<<<(XN4 + YN4 + 176 + 255) / 256, 256, 0, stream>>>(
        (const float4*)x, (const float4*)y, xb8, yt8, y2);
    knn_filter<<<dim3(NCHUNK, N_Q / QPB), 256, 0, stream>>>(xb8, yt8, y2, ckey);
    knn_finalize<<<N_Q / 8, 256, 0, stream>>>(ckey, x, y, labels, out);
}

// Round 17
// 226.229 us; speedup vs baseline: 1.2538x; 1.1856x over previous
//
#include <hip/hip_runtime.h>
#include <float.h>
#include <limits.h>

#define N_Q 8192
#define M_PTS 50000
#define DIM 128
#define KNN 10
#define NCLS 10
#define NCHUNK 16          // 16 chunks x 196 tiles (3136 tiles, 11 padded)
#define TPC 196            // tiles per chunk (uniform, compile-time)
#define CPC 8              // candidates kept per (query, chunk)
#define NCAND (NCHUNK*CPC) // 128 candidates per query
#define NSEL 24            // exact-rescored candidates (24 = proven margin; 20 failed R16)
#define TPL 4              // per-lane-class top depth (16 streams/chunk: safe)
#define QPB 128            // queries per block (4 waves x 32)
#define SBIAS 256.0f       // pre-added to y2: keys positive -> u32 order == float order
#define XN4 (N_Q*DIM/4)    // 262144 float4 in x
#define YN4 (M_PTS*DIM/4)  // 1600000 float4 in y

typedef __attribute__((ext_vector_type(8))) int i32x8;
typedef __attribute__((ext_vector_type(4))) float f32x4;
typedef unsigned int u32;

// ---------------------------------------------------------------------------
// fp32 -> e4m3 via the HW packed converter.
// ---------------------------------------------------------------------------
__device__ __forceinline__ u32 pack4_e4m3(float4 v, float sc) {
    u32 w = 0;
    w = __builtin_amdgcn_cvt_pk_fp8_f32(sc * v.x, sc * v.y, w, false);
    w = __builtin_amdgcn_cvt_pk_fp8_f32(sc * v.z, sc * v.w, w, true);
    return w;
}

// ---------------------------------------------------------------------------
// Prep (coalesced reads): xb8 = e4m3(-2x) row-major; yt8 = e4m3(y) tile
// records (2 KB/tile, slot l = g*16+nr: point nr, k in [32g,32g+32));
// y2 = ||y_j||^2 + SBIAS; pads 50000..50175 = FLT_MAX.
// ---------------------------------------------------------------------------
__global__ __launch_bounds__(256) void prep_kernel(
    const float4* __restrict__ x4, const float4* __restrict__ y4,
    u32* __restrict__ xb8, u32* __restrict__ yt8, float* __restrict__ y2) {
    int t = blockIdx.x * 256 + threadIdx.x;
    if (t < XN4) {
        xb8[t] = pack4_e4m3(x4[t], -2.0f);  // row-major: u32 idx == t
    } else if (t < XN4 + YN4) {
        int j = t - XN4;                    // float4 index into y
        int row = j >> 5;                   // point 0..49999
        int d4  = j & 31;                   // which float4 of the row
        float4 v = y4[j];
        u32 w = pack4_e4m3(v, 1.0f);
        int T = row >> 4, nr = row & 15;
        int g2 = d4 >> 3, s = d4 & 7;
        yt8[(size_t)T * 512 + (g2 * 16 + nr) * 8 + s] = w;
        float p = v.x * v.x + v.y * v.y + v.z * v.z + v.w * v.w;
        #pragma unroll
        for (int off = 16; off > 0; off >>= 1) p += __shfl_xor(p, off, 64);
        if (d4 == 0) y2[row] = p + SBIAS;
    } else if (t < XN4 + YN4 + 176) {
        y2[M_PTS + (t - XN4 - YN4)] = FLT_MAX;   // pad tiles: never selected
    }
}

// ---------------------------------------------------------------------------
// Filter = round-10 structure (best measured: 131 us): fp8 e4m3 16x16x128
// scaled-MFMA (unit scales), TWO query-sets per wave, C = y2+SBIAS splat
// (score = raw MFMA output), per-lane-class top-4 via bfi+min+3 med3
// (5 VALU/score). Empirical law (R10-R15): wall ~ 3.35 us per M
// wave-VALU-insts -> this is the known instruction-count minimum.
// No LDS/barriers in the K-loop. Grid 16x64 = 1024 = 4 blocks/CU.
// ---------------------------------------------------------------------------
__global__ __launch_bounds__(256, 4) void knn_filter(
    const u32* __restrict__ xb8, const u32* __restrict__ yt8,
    const float* __restrict__ y2, u32* __restrict__ ckey) {
    const int lane = threadIdx.x & 63;
    const int wid  = threadIdx.x >> 6;      // wave 0..3
    const int g    = lane >> 4;             // k-group 0..3
    const int nrow = lane & 15;             // point-in-tile (B col / C col)
    const int chunk = blockIdx.x;           // gridDim.x=16 -> XCD = chunk%8
    const int qb    = blockIdx.y;
    const int qw = qb * QPB + wid * 32;

    // A fragments: 2 query-sets, 8 dwords each (32 fp8 = k-slice 32g..32g+31)
    i32x8 a[2];
    #pragma unroll
    for (int s = 0; s < 2; ++s)
        a[s] = *(const i32x8*)(xb8 + (size_t)(qw + s * 16 + nrow) * 32 + g * 8);

    float ts[8][TPL];
    #pragma unroll
    for (int r = 0; r < 8; ++r)
        #pragma unroll
        for (int l = 0; l < TPL; ++l) ts[r][l] = FLT_MAX;

    const u32* ytp = yt8 + (size_t)chunk * TPC * 512 + lane * 8;
    const float* y2p = y2 + chunk * TPC * 16 + nrow;

    #pragma unroll 2
    for (int t = 0; t < TPC; ++t) {
        i32x8 b = *(const i32x8*)(ytp + (size_t)t * 512);
        float y2n = y2p[t * 16];
        f32x4 cq = {y2n, y2n, y2n, y2n};    // y2+SBIAS pre-loaded into C
        f32x4 d0 = __builtin_amdgcn_mfma_scale_f32_16x16x128_f8f6f4(
            a[0], b, cq, 0, 0, 0, 0x7F7F7F7F, 0, 0x7F7F7F7F);
        f32x4 d1 = __builtin_amdgcn_mfma_scale_f32_16x16x128_f8f6f4(
            a[1], b, cq, 0, 0, 0, 0x7F7F7F7F, 0, 0x7F7F7F7F);
        u32 rel = (u32)(t * 16) | (u32)nrow;          // < 3136, 12 bits
        #pragma unroll
        for (int i = 0; i < 4; ++i) {
            float key = __uint_as_float((__float_as_uint(d0[i]) & 0xFFFFF000u) | rel);
            float o0 = ts[i][0], o1 = ts[i][1], o2 = ts[i][2];
            ts[i][0] = fminf(o0, key);
            ts[i][1] = __builtin_amdgcn_fmed3f(key, o0, o1);
            ts[i][2] = __builtin_amdgcn_fmed3f(key, o1, o2);
            ts[i][3] = __builtin_amdgcn_fmed3f(key, o2, ts[i][3]);
        }
        #pragma unroll
        for (int i = 0; i < 4; ++i) {
            float key = __uint_as_float((__float_as_uint(d1[i]) & 0xFFFFF000u) | rel);
            float o0 = ts[4 + i][0], o1 = ts[4 + i][1], o2 = ts[4 + i][2];
            ts[4 + i][0] = fminf(o0, key);
            ts[4 + i][1] = __builtin_amdgcn_fmed3f(key, o0, o1);
            ts[4 + i][2] = __builtin_amdgcn_fmed3f(key, o1, o2);
            ts[4 + i][3] = __builtin_amdgcn_fmed3f(key, o2, ts[4 + i][3]);
        }
    }

    // ---- merge 16 lane-classes -> per-query sorted top-8 ----
    __shared__ u32 smem[QPB * 65];          // 33280 B
    #pragma unroll
    for (int s = 0; s < 2; ++s)
        #pragma unroll
        for (int r = 0; r < 4; ++r) {
            int ql = wid * 32 + s * 16 + g * 4 + r;
            #pragma unroll
            for (int l = 0; l < TPL; ++l)
                smem[ql * 65 + nrow * TPL + l] = __float_as_uint(ts[s * 4 + r][l]);
        }
    __syncthreads();
    if (threadIdx.x < QPB) {
        int ql = threadIdx.x;
        float bs[CPC];
        #pragma unroll
        for (int i = 0; i < CPC; ++i) bs[i] = FLT_MAX;
        for (int e = 0; e < 16 * TPL; ++e) {      // stride-65: conflict-free
            float f = __uint_as_float(smem[ql * 65 + e]);
            #pragma unroll
            for (int q2 = 0; q2 < CPC; ++q2) {
                float mn = fminf(bs[q2], f);
                f = fmaxf(bs[q2], f);
                bs[q2] = mn;
            }
        }
        u32* dst = ckey + ((size_t)(qb * QPB + ql) * NCHUNK + chunk) * CPC;
        #pragma unroll
        for (int i = 0; i < CPC; ++i) dst[i] = __float_as_uint(bs[i]);
    }
}

// ---------------------------------------------------------------------------
// Finalize: 8 queries/block, half-wave per query.
//  1. parallel exact-rank select of approx-top-24 from 128 keys (u32 compare
//     valid: keys positive via SBIAS; position tie-break -> unique ranks).
//  2. exact fp64 rescore, one candidate per sub-lane, 4-way split accums.
//  3. parallel top-10: each sub-lane ranks its candidate among the 24 by
//     (score,idx); rank<10 lanes write their LABEL (set is order-independent
//     for voting). Class ties -> LARGEST label (reference reversed-argmax).
// ---------------------------------------------------------------------------
__global__ __launch_bounds__(256) void knn_finalize(
    const u32* __restrict__ ckey, const float* __restrict__ x,
    const float* __restrict__ y, const int* __restrict__ labels,
    int* __restrict__ out) {
    const int lane = threadIdx.x & 63;
    const int wid  = threadIdx.x >> 6;
    const int qbase = blockIdx.x * 8;
    const int ql = wid * 2 + (lane >> 5);   // query-in-block 0..7
    const int sl = lane & 31;               // sub-lane in half-wave

    __shared__ u32 skey[8][NCAND];
    __shared__ int sidx[8][NSEL];
    __shared__ double sex[8][NSEL];
    __shared__ int slab[8][KNN];

    for (int i = threadIdx.x; i < 8 * NCAND; i += 256)
        skey[i >> 7][i & 127] = ckey[(size_t)(qbase + (i >> 7)) * NCAND + (i & 127)];
    __syncthreads();

    // 1. parallel rank select: 4 candidates per sub-lane, one kj read per j
    {
        u32 ke[4];
        int rank[4];
        #pragma unroll
        for (int r0 = 0; r0 < 4; ++r0) {
            ke[r0] = skey[ql][r0 * 32 + sl];
            rank[r0] = 0;
        }
        for (int j = 0; j < NCAND; ++j) {
            u32 kj = skey[ql][j];
            #pragma unroll
            for (int r0 = 0; r0 < 4; ++r0)
                rank[r0] += (kj < ke[r0] || (kj == ke[r0] && j < r0 * 32 + sl)) ? 1 : 0;
        }
        #pragma unroll
        for (int r0 = 0; r0 < 4; ++r0) {
            if (rank[r0] < NSEL) {
                int e = r0 * 32 + sl;
                sidx[ql][rank[r0]] = (e >> 3) * (TPC * 16) + (int)(ke[r0] & 0xFFFu);
            }
        }
    }
    __syncthreads();

    // 2. exact fp64 rescore (4-way split accumulators)
    int myidx = 0;
    if (sl < NSEL) {
        myidx = sidx[ql][sl];
        const float4* xr = (const float4*)(x + (size_t)(qbase + ql) * DIM);
        const float4* yr = (const float4*)(y + (size_t)myidx * DIM);
        double dy[4] = {0.0, 0.0, 0.0, 0.0};
        double dx[4] = {0.0, 0.0, 0.0, 0.0};
        #pragma unroll
        for (int i = 0; i < 32; ++i) {
            float4 yv = yr[i];
            float4 xv = xr[i];
            int k = i & 3;
            dy[k] = fma((double)yv.x, (double)yv.x, dy[k]);
            dy[k] = fma((double)yv.y, (double)yv.y, dy[k]);
            dy[k] = fma((double)yv.z, (double)yv.z, dy[k]);
            dy[k] = fma((double)yv.w, (double)yv.w, dy[k]);
            dx[k] = fma((double)xv.x, (double)yv.x, dx[k]);
            dx[k] = fma((double)xv.y, (double)yv.y, dx[k]);
            dx[k] = fma((double)xv.z, (double)yv.z, dx[k]);
            dx[k] = fma((double)xv.w, (double)yv.w, dx[k]);
        }
        sex[ql][sl] = ((dy[0] + dy[1]) + (dy[2] + dy[3]))
                    - 2.0 * ((dx[0] + dx[1]) + (dx[2] + dx[3]));
    }
    __syncthreads();

    // 3. parallel top-10: rank my candidate among the 24 by (score, idx)
    if (sl < NSEL) {
        double s = sex[ql][sl];
        int cnt = 0;
        #pragma unroll
        for (int j = 0; j < NSEL; ++j) {
            double sj = sex[ql][j];
            cnt += (sj < s || (sj == s && sidx[ql][j] < myidx)) ? 1 : 0;
        }
        if (cnt < KNN) slab[ql][cnt] = labels[myidx];
    }
    __syncthreads();

    if (sl == 0) {
        int lab[KNN];
        #pragma unroll
        for (int i = 0; i < KNN; ++i) lab[i] = slab[ql][i];
        int bestc = 0, bestn = -1;
        #pragma unroll
        for (int c = 0; c < NCLS; ++c) {
            int n = 0;
            #pragma unroll
            for (int i = 0; i < KNN; ++i) n += (lab[i] == c) ? 1 : 0;
            if (n >= bestn) { bestn = n; bestc = c; }   // >= : ties -> larger label
        }
        out[qbase + ql] = bestc;
    }
}

// ---------------------------------------------------------------------------
extern "C" void kernel_launch(void* const* d_in, const int* in_sizes, int n_in,
                              void* d_out, int out_size, void* d_ws, size_t ws_size,
                              hipStream_t stream) {
    const float* x      = (const float*)d_in[0];
    const float* y      = (const float*)d_in[1];
    const int*   labels = (const int*)d_in[2];
    // d_in[3] is k == 10, baked in.

    char* ws = (char*)d_ws;
    size_t off = 0;
    u32* xb8 = (u32*)(ws + off);    off += (size_t)N_Q * DIM;            //  1.05 MB
    u32* yt8 = (u32*)(ws + off);    off += (size_t)NCHUNK * TPC * 2048;  //  6.42 MB
    float* y2 = (float*)(ws + off); off += (size_t)NCHUNK * TPC * 16 * 4;//  0.20 MB
    u32* ckey = (u32*)(ws + off);   off += (size_t)N_Q * NCAND * 4;      //  4.19 MB
    int* out = (int*)d_out;

    prep_kernel<<<(XN4 + YN4 + 176 + 255) / 256, 256, 0, stream>>>(
        (const float4*)x, (const float4*)y, xb8, yt8, y2);
    knn_filter<<<dim3(NCHUNK, N_Q / QPB), 256, 0, stream>>>(xb8, yt8, y2, ckey);
    knn_finalize<<<N_Q / 8, 256, 0, stream>>>(ckey, x, y, labels, out);
}